// Round 2
// baseline (532.444 us; speedup 1.0000x reference)
//
#include <hip/hip_runtime.h>
#include <hip/hip_bf16.h>
#include <stdint.h>

// GraphNet global block, MI355X.
// R1 change: counting-sort nodes by graph id, then per-block LDS slot
// aggregation -> global atomic count drops 32M -> ~0.75M (theory: node_kernel
// was atomic-throughput-bound: WRITE_SIZE 125 MB == atomic bytes, all pipes
// <15%). Phase 2 rewritten as f16 MFMA (old version re-read 160KB weights per
// wave). agg buffer aliases d_out (read before overwrite, block-exclusive rows).
// R2: identical resubmit (R1 bench failed with GPUAcquisitionTimeout).

#define NNODES 500000
#define NGRAPHS 4096
#define ROWS 128      // node rows per block
#define LDH 136       // padded f16 row stride (272 B: 16B-aligned, conflict-free)
#define SLOTS 16      // max distinct graphs per 128 sorted rows before fallback

typedef __attribute__((ext_vector_type(8))) _Float16 half8;
typedef __attribute__((ext_vector_type(4))) float floatx4;

// ---------------- prep: transpose all six weights to f16 [N][K] -------------
__global__ void prep_kernel(const float* __restrict__ w1, const float* __restrict__ w2,
                            const float* __restrict__ w3, const float* __restrict__ w4,
                            const float* __restrict__ w5, const float* __restrict__ w6,
                            _Float16* __restrict__ w1T, _Float16* __restrict__ w2T,
                            _Float16* __restrict__ w3T, _Float16* __restrict__ w4T,
                            _Float16* __restrict__ w5T, _Float16* __restrict__ w6T) {
    int i = blockIdx.x * 256 + threadIdx.x;   // 0..16383
    if (i < 128 * 128) {
        int n = i >> 7, k = i & 127;
        w1T[i] = (_Float16)w1[k * 128 + n];
        w2T[i] = (_Float16)w2[k * 128 + n];
        w4T[i] = (_Float16)w4[k * 128 + n];
        w5T[i] = (_Float16)w5[k * 128 + n];
    }
    if (i < 64 * 128) {
        int n = i >> 7, k = i & 127;
        w3T[i] = (_Float16)w3[k * 64 + n];
        w6T[i] = (_Float16)w6[k * 64 + n];
    }
}

// ---------------- counting sort: hist -> scan -> scatter --------------------
__global__ void hist_kernel(const int* __restrict__ batch, int* __restrict__ cnt) {
    __shared__ int h[NGRAPHS];
    for (int i = threadIdx.x; i < NGRAPHS; i += 256) h[i] = 0;
    __syncthreads();
    for (int i = blockIdx.x * 256 + threadIdx.x; i < NNODES; i += 64 * 256)
        atomicAdd(&h[batch[i]], 1);
    __syncthreads();
    for (int i = threadIdx.x; i < NGRAPHS; i += 256) {
        int v = h[i];
        if (v) atomicAdd(&cnt[i], v);
    }
}

__global__ void scan_kernel(const int* __restrict__ cnt, int* __restrict__ runoff) {
    // single block, 256 threads, 16 bins each -> exclusive prefix sum
    __shared__ int partial[256];
    int tid = threadIdx.x;
    int local[16];
    int s = 0;
    #pragma unroll
    for (int j = 0; j < 16; ++j) { local[j] = cnt[tid * 16 + j]; s += local[j]; }
    partial[tid] = s;
    __syncthreads();
    for (int off = 1; off < 256; off <<= 1) {
        int v = (tid >= off) ? partial[tid - off] : 0;
        __syncthreads();
        partial[tid] += v;
        __syncthreads();
    }
    int run = partial[tid] - s;   // exclusive base for this thread's 16 bins
    #pragma unroll
    for (int j = 0; j < 16; ++j) { runoff[tid * 16 + j] = run; run += local[j]; }
}

__global__ void scatter_kernel(const int* __restrict__ batch, int* __restrict__ runoff,
                               int* __restrict__ perm, int* __restrict__ sbat) {
    int i = blockIdx.x * 256 + threadIdx.x;
    if (i < NNODES) {
        int g = batch[i];
        int p = atomicAdd(&runoff[g], 1);
        perm[p] = i;
        sbat[p] = g;
    }
}

// ---------------- phase 1: per-node MLP + LN + slot-aggregated scatter ------
__global__ __launch_bounds__(256, 2) void node_kernel(
    const float* __restrict__ x, const float* __restrict__ u,
    const int* __restrict__ perm, const int* __restrict__ sbat,
    const _Float16* __restrict__ w1T, const _Float16* __restrict__ w2T,
    const _Float16* __restrict__ w3T,
    const float* __restrict__ b1, const float* __restrict__ b2, const float* __restrict__ b3,
    const float* __restrict__ lng, const float* __restrict__ lnb,
    float* __restrict__ agg)
{
    __shared__ __align__(16) _Float16 hA[ROWS * LDH];
    __shared__ int sBatch[ROWS];
    __shared__ int sPerm[ROWS];
    __shared__ float aggS[SLOTS * 64];

    const int tid = threadIdx.x;
    const int rowbase = blockIdx.x * ROWS;
    const int wave = tid >> 6;
    const int lane = tid & 63;
    const int q = lane >> 4;      // quad (k-block / row-block selector)
    const int l16 = lane & 15;

    // stage sorted node ids + graph ids; zero slot accumulators
    for (int r = tid; r < ROWS; r += 256) {
        int gr = rowbase + r;
        sPerm[r] = (gr < NNODES) ? perm[gr] : -1;
        sBatch[r] = (gr < NNODES) ? sbat[gr] : 0;
    }
    for (int i = tid; i < SLOTS * 64; i += 256) aggS[i] = 0.f;
    __syncthreads();

    const int nValid = (rowbase + ROWS <= NNODES) ? ROWS : (NNODES - rowbase);
    const int gFirst = sBatch[0];
    const int nSlots = sBatch[nValid - 1] - gFirst + 1;   // sorted -> contiguous span
    const bool useLds = (nSlots <= SLOTS);

    // stage h0 = concat(x[perm[r]], u[batch]) as f16
    for (int i = tid; i < ROWS * 16; i += 256) {
        int r = i >> 4, c4 = (i & 15) << 2;
        int nid = sPerm[r];
        float4 vx = make_float4(0.f, 0.f, 0.f, 0.f);
        if (nid >= 0) vx = *(const float4*)(x + (size_t)nid * 64 + c4);
        _Float16* p = &hA[r * LDH + c4];
        p[0] = (_Float16)vx.x; p[1] = (_Float16)vx.y;
        p[2] = (_Float16)vx.z; p[3] = (_Float16)vx.w;
        int g = sBatch[r];
        float4 vu = *(const float4*)(u + (size_t)g * 64 + c4);
        _Float16* p2 = &hA[r * LDH + 64 + c4];
        p2[0] = (_Float16)vu.x; p2[1] = (_Float16)vu.y;
        p2[2] = (_Float16)vu.z; p2[3] = (_Float16)vu.w;
    }
    __syncthreads();

    // ---- layers 1 & 2: 128x128, relu, in-place in hA ----
    const int rowg = (wave >> 1) * 64;
    const int colg = (wave & 1) * 64;
    for (int layer = 0; layer < 2; ++layer) {
        const _Float16* wT = layer ? w2T : w1T;
        const float* bias = layer ? b2 : b1;
        floatx4 acc[4][4];
        #pragma unroll
        for (int ct = 0; ct < 4; ++ct) {
            float bv = bias[colg + ct * 16 + l16];
            #pragma unroll
            for (int rt = 0; rt < 4; ++rt) acc[rt][ct] = (floatx4){bv, bv, bv, bv};
        }
        half8 bfr[4][4];
        #pragma unroll
        for (int ks = 0; ks < 4; ++ks)
            #pragma unroll
            for (int ct = 0; ct < 4; ++ct)
                bfr[ks][ct] = *(const half8*)(wT + (colg + ct * 16 + l16) * 128 + ks * 32 + q * 8);
        #pragma unroll
        for (int ks = 0; ks < 4; ++ks) {
            half8 af[4];
            #pragma unroll
            for (int rt = 0; rt < 4; ++rt)
                af[rt] = *(const half8*)(&hA[(rowg + rt * 16 + l16) * LDH + ks * 32 + q * 8]);
            #pragma unroll
            for (int rt = 0; rt < 4; ++rt)
                #pragma unroll
                for (int ct = 0; ct < 4; ++ct)
                    acc[rt][ct] = __builtin_amdgcn_mfma_f32_16x16x32_f16(
                        af[rt], bfr[ks][ct], acc[rt][ct], 0, 0, 0);
        }
        __syncthreads();   // all reads of hA complete
        #pragma unroll
        for (int rt = 0; rt < 4; ++rt)
            #pragma unroll
            for (int ct = 0; ct < 4; ++ct)
                #pragma unroll
                for (int j = 0; j < 4; ++j) {
                    float v = acc[rt][ct][j];
                    v = v > 0.f ? v : 0.f;
                    hA[(rowg + rt * 16 + q * 4 + j) * LDH + colg + ct * 16 + l16] = (_Float16)v;
                }
        __syncthreads();   // writes visible
    }

    // ---- layer 3: 128x64 + LN + slot aggregation ----
    {
        const int rowg3 = wave * 32;   // 4 waves x 32 rows
        floatx4 acc[2][4];
        #pragma unroll
        for (int ct = 0; ct < 4; ++ct) {
            float bv = b3[ct * 16 + l16];
            acc[0][ct] = (floatx4){bv, bv, bv, bv};
            acc[1][ct] = (floatx4){bv, bv, bv, bv};
        }
        half8 bfr[4][4];
        #pragma unroll
        for (int ks = 0; ks < 4; ++ks)
            #pragma unroll
            for (int ct = 0; ct < 4; ++ct)
                bfr[ks][ct] = *(const half8*)(w3T + (ct * 16 + l16) * 128 + ks * 32 + q * 8);
        #pragma unroll
        for (int ks = 0; ks < 4; ++ks) {
            half8 af[2];
            #pragma unroll
            for (int rt = 0; rt < 2; ++rt)
                af[rt] = *(const half8*)(&hA[(rowg3 + rt * 16 + l16) * LDH + ks * 32 + q * 8]);
            #pragma unroll
            for (int rt = 0; rt < 2; ++rt)
                #pragma unroll
                for (int ct = 0; ct < 4; ++ct)
                    acc[rt][ct] = __builtin_amdgcn_mfma_f32_16x16x32_f16(
                        af[rt], bfr[ks][ct], acc[rt][ct], 0, 0, 0);
        }
        float gct[4], bct[4];
        #pragma unroll
        for (int ct = 0; ct < 4; ++ct) {
            gct[ct] = lng[ct * 16 + l16];
            bct[ct] = lnb[ct * 16 + l16];
        }
        #pragma unroll
        for (int rt = 0; rt < 2; ++rt)
            #pragma unroll
            for (int j = 0; j < 4; ++j) {
                int rloc = rowg3 + rt * 16 + q * 4 + j;   // quad-uniform row
                float v0 = acc[rt][0][j], v1 = acc[rt][1][j];
                float v2 = acc[rt][2][j], v3 = acc[rt][3][j];
                float s = v0 + v1 + v2 + v3;
                float ss = v0 * v0 + v1 * v1 + v2 * v2 + v3 * v3;
                #pragma unroll
                for (int m = 1; m < 16; m <<= 1) {
                    s += __shfl_xor(s, m, 16);
                    ss += __shfl_xor(ss, m, 16);
                }
                float mean = s * (1.f / 64.f);
                float var = ss * (1.f / 64.f) - mean * mean;
                float rstd = rsqrtf(var + 1e-5f);
                if (rowbase + rloc < NNODES) {
                    float o0 = (v0 - mean) * rstd * gct[0] + bct[0];
                    float o1 = (v1 - mean) * rstd * gct[1] + bct[1];
                    float o2 = (v2 - mean) * rstd * gct[2] + bct[2];
                    float o3 = (v3 - mean) * rstd * gct[3] + bct[3];
                    if (useLds) {
                        float* dst = aggS + (sBatch[rloc] - gFirst) * 64;
                        atomicAdd(dst + 0 + l16,  o0);
                        atomicAdd(dst + 16 + l16, o1);
                        atomicAdd(dst + 32 + l16, o2);
                        atomicAdd(dst + 48 + l16, o3);
                    } else {   // safety fallback: >SLOTS graphs in this window
                        float* dst = agg + (size_t)sBatch[rloc] * 64;
                        unsafeAtomicAdd(dst + 0 + l16,  o0);
                        unsafeAtomicAdd(dst + 16 + l16, o1);
                        unsafeAtomicAdd(dst + 32 + l16, o2);
                        unsafeAtomicAdd(dst + 48 + l16, o3);
                    }
                }
            }
    }
    __syncthreads();
    if (useLds) {
        for (int i = tid; i < nSlots * 64; i += 256)
            unsafeAtomicAdd(agg + (size_t)(gFirst + (i >> 6)) * 64 + (i & 63), aggS[i]);
    }
}

// ---------------- phase 2: per-graph MLP, f16 MFMA (32 blocks x 128 rows) ---
__global__ __launch_bounds__(256, 2) void graph2_kernel(
    const float* __restrict__ u,
    const _Float16* __restrict__ w4T, const _Float16* __restrict__ w5T,
    const _Float16* __restrict__ w6T,
    const float* __restrict__ b4, const float* __restrict__ b5, const float* __restrict__ b6,
    const float* __restrict__ lng, const float* __restrict__ lnb,
    float* __restrict__ out)   // out holds agg on entry; rows block-exclusive
{
    __shared__ __align__(16) _Float16 hA[128 * LDH];

    const int tid = threadIdx.x;
    const int rowbase = blockIdx.x * 128;
    const int wave = tid >> 6;
    const int lane = tid & 63;
    const int q = lane >> 4;
    const int l16 = lane & 15;

    // stage g0 = concat(agg, u) as f16
    for (int i = tid; i < 128 * 16; i += 256) {
        int r = i >> 4, c4 = (i & 15) << 2;
        int g = rowbase + r;
        float4 va = *(const float4*)(out + (size_t)g * 64 + c4);
        _Float16* p = &hA[r * LDH + c4];
        p[0] = (_Float16)va.x; p[1] = (_Float16)va.y;
        p[2] = (_Float16)va.z; p[3] = (_Float16)va.w;
        float4 vu = *(const float4*)(u + (size_t)g * 64 + c4);
        _Float16* p2 = &hA[r * LDH + 64 + c4];
        p2[0] = (_Float16)vu.x; p2[1] = (_Float16)vu.y;
        p2[2] = (_Float16)vu.z; p2[3] = (_Float16)vu.w;
    }
    __syncthreads();

    // ---- layers 4 & 5: 128x128, relu, in-place ----
    const int rowg = (wave >> 1) * 64;
    const int colg = (wave & 1) * 64;
    for (int layer = 0; layer < 2; ++layer) {
        const _Float16* wT = layer ? w5T : w4T;
        const float* bias = layer ? b5 : b4;
        floatx4 acc[4][4];
        #pragma unroll
        for (int ct = 0; ct < 4; ++ct) {
            float bv = bias[colg + ct * 16 + l16];
            #pragma unroll
            for (int rt = 0; rt < 4; ++rt) acc[rt][ct] = (floatx4){bv, bv, bv, bv};
        }
        half8 bfr[4][4];
        #pragma unroll
        for (int ks = 0; ks < 4; ++ks)
            #pragma unroll
            for (int ct = 0; ct < 4; ++ct)
                bfr[ks][ct] = *(const half8*)(wT + (colg + ct * 16 + l16) * 128 + ks * 32 + q * 8);
        #pragma unroll
        for (int ks = 0; ks < 4; ++ks) {
            half8 af[4];
            #pragma unroll
            for (int rt = 0; rt < 4; ++rt)
                af[rt] = *(const half8*)(&hA[(rowg + rt * 16 + l16) * LDH + ks * 32 + q * 8]);
            #pragma unroll
            for (int rt = 0; rt < 4; ++rt)
                #pragma unroll
                for (int ct = 0; ct < 4; ++ct)
                    acc[rt][ct] = __builtin_amdgcn_mfma_f32_16x16x32_f16(
                        af[rt], bfr[ks][ct], acc[rt][ct], 0, 0, 0);
        }
        __syncthreads();
        #pragma unroll
        for (int rt = 0; rt < 4; ++rt)
            #pragma unroll
            for (int ct = 0; ct < 4; ++ct)
                #pragma unroll
                for (int j = 0; j < 4; ++j) {
                    float v = acc[rt][ct][j];
                    v = v > 0.f ? v : 0.f;
                    hA[(rowg + rt * 16 + q * 4 + j) * LDH + colg + ct * 16 + l16] = (_Float16)v;
                }
        __syncthreads();
    }

    // ---- layer 6: 128x64 + LN + residual + store ----
    {
        const int rowg3 = wave * 32;
        floatx4 acc[2][4];
        #pragma unroll
        for (int ct = 0; ct < 4; ++ct) {
            float bv = b6[ct * 16 + l16];
            acc[0][ct] = (floatx4){bv, bv, bv, bv};
            acc[1][ct] = (floatx4){bv, bv, bv, bv};
        }
        half8 bfr[4][4];
        #pragma unroll
        for (int ks = 0; ks < 4; ++ks)
            #pragma unroll
            for (int ct = 0; ct < 4; ++ct)
                bfr[ks][ct] = *(const half8*)(w6T + (ct * 16 + l16) * 128 + ks * 32 + q * 8);
        #pragma unroll
        for (int ks = 0; ks < 4; ++ks) {
            half8 af[2];
            #pragma unroll
            for (int rt = 0; rt < 2; ++rt)
                af[rt] = *(const half8*)(&hA[(rowg3 + rt * 16 + l16) * LDH + ks * 32 + q * 8]);
            #pragma unroll
            for (int rt = 0; rt < 2; ++rt)
                #pragma unroll
                for (int ct = 0; ct < 4; ++ct)
                    acc[rt][ct] = __builtin_amdgcn_mfma_f32_16x16x32_f16(
                        af[rt], bfr[ks][ct], acc[rt][ct], 0, 0, 0);
        }
        float gct[4], bct[4];
        #pragma unroll
        for (int ct = 0; ct < 4; ++ct) {
            gct[ct] = lng[ct * 16 + l16];
            bct[ct] = lnb[ct * 16 + l16];
        }
        #pragma unroll
        for (int rt = 0; rt < 2; ++rt)
            #pragma unroll
            for (int j = 0; j < 4; ++j) {
                int rloc = rowg3 + rt * 16 + q * 4 + j;
                size_t g = (size_t)(rowbase + rloc);
                float v0 = acc[rt][0][j], v1 = acc[rt][1][j];
                float v2 = acc[rt][2][j], v3 = acc[rt][3][j];
                float s = v0 + v1 + v2 + v3;
                float ss = v0 * v0 + v1 * v1 + v2 * v2 + v3 * v3;
                #pragma unroll
                for (int m = 1; m < 16; m <<= 1) {
                    s += __shfl_xor(s, m, 16);
                    ss += __shfl_xor(ss, m, 16);
                }
                float mean = s * (1.f / 64.f);
                float var = ss * (1.f / 64.f) - mean * mean;
                float rstd = rsqrtf(var + 1e-5f);
                out[g * 64 + 0 + l16]  = (v0 - mean) * rstd * gct[0] + bct[0] + u[g * 64 + 0 + l16];
                out[g * 64 + 16 + l16] = (v1 - mean) * rstd * gct[1] + bct[1] + u[g * 64 + 16 + l16];
                out[g * 64 + 32 + l16] = (v2 - mean) * rstd * gct[2] + bct[2] + u[g * 64 + 32 + l16];
                out[g * 64 + 48 + l16] = (v3 - mean) * rstd * gct[3] + bct[3] + u[g * 64 + 48 + l16];
            }
    }
}

extern "C" void kernel_launch(void* const* d_in, const int* in_sizes, int n_in,
                              void* d_out, int out_size, void* d_ws, size_t ws_size,
                              hipStream_t stream) {
    const float* x   = (const float*)d_in[0];
    const float* u   = (const float*)d_in[1];
    const int*   bt  = (const int*)d_in[2];
    const float* w1  = (const float*)d_in[3];
    const float* b1  = (const float*)d_in[4];
    const float* w2  = (const float*)d_in[5];
    const float* b2  = (const float*)d_in[6];
    const float* w3  = (const float*)d_in[7];
    const float* b3  = (const float*)d_in[8];
    const float* lng = (const float*)d_in[9];
    const float* lnb = (const float*)d_in[10];
    const float* w4  = (const float*)d_in[11];
    const float* b4  = (const float*)d_in[12];
    const float* w5  = (const float*)d_in[13];
    const float* b5  = (const float*)d_in[14];
    const float* w6  = (const float*)d_in[15];
    const float* b6  = (const float*)d_in[16];
    const float* g2  = (const float*)d_in[17];
    const float* bb2 = (const float*)d_in[18];
    float* out = (float*)d_out;

    // workspace layout: 6 f16 weight transposes (160 KB) + sort arrays (~4 MB)
    _Float16* w1T = (_Float16*)d_ws;
    _Float16* w2T = w1T + 128 * 128;
    _Float16* w3T = w2T + 128 * 128;
    _Float16* w4T = w3T + 64 * 128;
    _Float16* w5T = w4T + 128 * 128;
    _Float16* w6T = w5T + 128 * 128;
    int* cnt    = (int*)(w6T + 64 * 128);
    int* runoff = cnt + NGRAPHS;
    int* perm   = runoff + NGRAPHS;
    int* sbat   = perm + NNODES;

    hipMemsetAsync(d_out, 0, (size_t)NGRAPHS * 64 * sizeof(float), stream);
    hipMemsetAsync(cnt, 0, (size_t)NGRAPHS * sizeof(int), stream);
    prep_kernel<<<64, 256, 0, stream>>>(w1, w2, w3, w4, w5, w6,
                                        w1T, w2T, w3T, w4T, w5T, w6T);
    hist_kernel<<<64, 256, 0, stream>>>(bt, cnt);
    scan_kernel<<<1, 256, 0, stream>>>(cnt, runoff);
    scatter_kernel<<<(NNODES + 255) / 256, 256, 0, stream>>>(bt, runoff, perm, sbat);
    node_kernel<<<(NNODES + ROWS - 1) / ROWS, 256, 0, stream>>>(
        x, u, perm, sbat, w1T, w2T, w3T, b1, b2, b3, lng, lnb, out);
    graph2_kernel<<<NGRAPHS / 128, 256, 0, stream>>>(
        u, w4T, w5T, w6T, b4, b5, b6, g2, bb2, out);
}